// Round 5
// baseline (194.156 us; speedup 1.0000x reference)
//
#include <hip/hip_runtime.h>

typedef unsigned int uint;
typedef unsigned short ushort;
typedef unsigned char uchar;

// AirMPNN R5.
// p[n] = sigmoid(mlp1(xc[n])) per NODE (mlp1 depends only on source node).
// Edge phase: one per-call bucket partition (dst>>9) with slim LDS multisplit
// (21KB -> ~7 blocks/CU), then 3 rounds of {split-8 LDS aggregation ->
// aggpart (no global atomics), node MLP}.

#define NPB 512        // nodes per bucket
#define NPB_SHIFT 9
#define MAXB 256       // max buckets (N <= 131072)
#define CHUNK 2048     // edges per partition block (slim LDS)
#define S_SPLIT 8      // sub-blocks per bucket in aggregation
#define NBLK_H 1024

__device__ __forceinline__ void load_smem(float* dstp, const float* __restrict__ srcp,
                                          int n, int tid, int nthreads) {
    for (int i = tid; i < n; i += nthreads) dstp[i] = srcp[i];
}

// sigmoid(mlp1(xj)): 9 -> 32 relu -> 32 relu -> 1 sigmoid
__device__ __forceinline__ float mlp1_eval(const float* xj,
    const float* sW1, const float* sb1, const float* sW2, const float* sb2,
    const float* sW3, float sb3)
{
    float h1[32];
#pragma unroll
    for (int j = 0; j < 32; ++j) h1[j] = sb1[j];
#pragma unroll
    for (int i = 0; i < 9; ++i) {
        float v = xj[i];
#pragma unroll
        for (int j = 0; j < 32; ++j) h1[j] = fmaf(v, sW1[i*32+j], h1[j]);
    }
#pragma unroll
    for (int j = 0; j < 32; ++j) h1[j] = fmaxf(h1[j], 0.0f);
    float h2[32];
#pragma unroll
    for (int j = 0; j < 32; ++j) h2[j] = sb2[j];
#pragma unroll
    for (int i = 0; i < 32; ++i) {
        float v = h1[i];
#pragma unroll
        for (int j = 0; j < 32; ++j) h2[j] = fmaf(v, sW2[i*32+j], h2[j]);
    }
    float m = sb3;
#pragma unroll
    for (int i = 0; i < 32; ++i) m = fmaf(fmaxf(h2[i], 0.0f), sW3[i], m);
    return 1.0f / (1.0f + __expf(-m));
}

// p0: p[n] = sigmoid(mlp1(x[n])); block 0 zeroes count[]; fallback zeroes agg3
__global__ __launch_bounds__(256) void p0_kernel(
    const float* __restrict__ x,
    const float* __restrict__ W1, const float* __restrict__ b1,
    const float* __restrict__ W2, const float* __restrict__ b2,
    const float* __restrict__ W3, const float* __restrict__ b3,
    float* __restrict__ p, uint* __restrict__ count, float* __restrict__ agg3, int N)
{
    __shared__ float sW1[288], sb1[32], sW2[1024], sb2[32], sW3[32], sb3s[1];
    int tid = threadIdx.x;
    load_smem(sW1, W1, 288, tid, 256);
    load_smem(sb1, b1, 32, tid, 256);
    load_smem(sW2, W2, 1024, tid, 256);
    load_smem(sb2, b2, 32, tid, 256);
    load_smem(sW3, W3, 32, tid, 256);
    if (tid == 0) sb3s[0] = b3[0];
    __syncthreads();
    if (count && blockIdx.x == 0) count[tid] = 0u;   // MAXB == 256
    int n = blockIdx.x * 256 + tid;
    if (n >= N) return;
    if (agg3) { agg3[n] = 0.0f; agg3[N + n] = 0.0f; agg3[2*(size_t)N + n] = 0.0f; }
    float xj[9];
#pragma unroll
    for (int i = 0; i < 9; ++i) xj[i] = x[(size_t)n*9 + i];
    p[n] = mlp1_eval(xj, sW1, sb1, sW2, sb2, sW3, sb3s[0]);
}

// bin totals: LDS hist + one global atomic per (block,bin)
__global__ __launch_bounds__(256) void hist_kernel2(
    const int* __restrict__ dst, uint* __restrict__ count, int E, int B)
{
    __shared__ uint hist[MAXB];
    int tid = threadIdx.x;
    for (int i = tid; i < MAXB; i += 256) hist[i] = 0u;
    __syncthreads();
    int total = gridDim.x * 256;
    int gid = blockIdx.x * 256 + tid;
    int E4 = E >> 2;
    const int4* dst4 = (const int4*)dst;
    for (int i = gid; i < E4; i += total) {
        int4 d = dst4[i];
        atomicAdd(&hist[((uint)d.x) >> NPB_SHIFT], 1u);
        atomicAdd(&hist[((uint)d.y) >> NPB_SHIFT], 1u);
        atomicAdd(&hist[((uint)d.z) >> NPB_SHIFT], 1u);
        atomicAdd(&hist[((uint)d.w) >> NPB_SHIFT], 1u);
    }
    for (int e = 4*E4 + gid; e < E; e += total)
        atomicAdd(&hist[((uint)dst[e]) >> NPB_SHIFT], 1u);
    __syncthreads();
    for (int b = tid; b < B; b += 256)
        if (hist[b]) atomicAdd(&count[b], hist[b]);
}

// exclusive scan of count -> base[], cursor[]; base[B] = E
__global__ __launch_bounds__(256) void scan_kernel(
    const uint* __restrict__ count, uint* __restrict__ base,
    uint* __restrict__ cursor, int B)
{
    __shared__ uint s[MAXB];
    int t = threadIdx.x;
    uint v = (t < B) ? count[t] : 0u;
    s[t] = v;
    __syncthreads();
    for (int off = 1; off < MAXB; off <<= 1) {
        uint xv = (t >= off) ? s[t - off] : 0u;
        __syncthreads();
        s[t] += xv;
        __syncthreads();
    }
    uint excl = s[t] - v;
    if (t < B) { base[t] = excl; cursor[t] = excl; }
    else       { cursor[t] = 0u; }
    if (t == B - 1) base[B] = s[t];
}

// Slim LDS multisplit partition (21KB LDS): coalesced reads, mostly-coalesced
// writes (runs of ~CHUNK/B edges), bump allocation via global cursor.
// Keys are re-read in pass 2 (chunk is L1/L2-resident after pass 1).
__global__ __launch_bounds__(256) void partition_kernel(
    const int* __restrict__ dst, const int* __restrict__ src,
    const float* __restrict__ ea, uint* __restrict__ cursor,
    int2* __restrict__ ia, int E, int B)
{
    __shared__ uint hist[MAXB];       // counts, then per-bin local cursor
    __shared__ uint lbase[MAXB];      // local exclusive offsets
    __shared__ uint gbase[MAXB];      // reserved global base per bin
    __shared__ int2  payload[CHUNK];  // locally-sorted payload
    __shared__ uchar sbin[CHUNK];     // bin per sorted slot
    int tid = threadIdx.x;
    int start = blockIdx.x * CHUNK;
    int n = min(E - start, CHUNK);
    hist[tid] = 0u;
    __syncthreads();
    // pass 1: count bins
    for (int i = tid; i < n; i += 256)
        atomicAdd(&hist[((uint)dst[start + i]) >> NPB_SHIFT], 1u);
    __syncthreads();
    // block scan (Hillis-Steele) of hist into lbase
    uint cnt_b = hist[tid];
    lbase[tid] = cnt_b;
    __syncthreads();
    for (int o = 1; o < MAXB; o <<= 1) {
        uint xv = (tid >= o) ? lbase[tid - o] : 0u;
        __syncthreads();
        lbase[tid] += xv;
        __syncthreads();
    }
    uint excl = lbase[tid] - cnt_b;
    gbase[tid] = cnt_b ? atomicAdd(&cursor[tid], cnt_b) : 0u;  // reserve space
    lbase[tid] = excl;
    hist[tid]  = excl;   // local placement cursor
    __syncthreads();
    // pass 2: re-read keys, place into LDS-sorted order
    for (int i = tid; i < n; i += 256) {
        uint d = (uint)dst[start + i];
        uint b = d >> NPB_SHIFT;
        uint s = atomicAdd(&hist[b], 1u);
        int2 v;
        v.x = (int)(((uint)src[start + i] << NPB_SHIFT) | (d & (NPB - 1)));
        v.y = __float_as_int(ea[start + i]);
        payload[s] = v;
        sbin[s] = (uchar)b;
    }
    __syncthreads();
    // pass 3: write runs (consecutive s within a bin -> consecutive global)
    for (int s2 = tid; s2 < n; s2 += 256) {
        uint b = sbin[s2];
        ia[gbase[b] + ((uint)s2 - lbase[b])] = payload[s2];
    }
}

// split-8 aggregation: each sub-block sums its strided share into LDS,
// stores 512 partial sums coalesced (no global atomics).
__global__ __launch_bounds__(512) void agg_kernel(
    const int2* __restrict__ ia, const uint* __restrict__ base,
    const float* __restrict__ p_in, float* __restrict__ aggpart)
{
    __shared__ float aggl[NPB];
    int tid = threadIdx.x;
    int bkt = blockIdx.x / S_SPLIT;
    int sub = blockIdx.x % S_SPLIT;
    aggl[tid] = 0.0f;
    __syncthreads();
    uint e0 = base[bkt], e1 = base[bkt + 1];
    for (uint e = e0 + (uint)sub * 512u + (uint)tid; e < e1; e += S_SPLIT * 512u) {
        int2 v = ia[e];
        atomicAdd(&aggl[(uint)v.x & (NPB - 1)],
                  p_in[(uint)v.x >> NPB_SHIFT] * __int_as_float(v.y));
    }
    __syncthreads();
    aggpart[(size_t)blockIdx.x * NPB + tid] = aggl[tid];
}

// node MLP per bucket (512 threads = 512 nodes); sums S_SPLIT parts.
// xin==xout in-place is safe: each thread touches only its own row.
template<bool LAST>
__global__ __launch_bounds__(512) void node_kernel2(
    const float* __restrict__ xin, const float* __restrict__ aggpart,
    const float* __restrict__ V1, const float* __restrict__ c1,
    const float* __restrict__ V2, const float* __restrict__ c2,
    const float* __restrict__ W1, const float* __restrict__ b1,
    const float* __restrict__ W2, const float* __restrict__ b2,
    const float* __restrict__ W3, const float* __restrict__ b3,
    const float* __restrict__ H1, const float* __restrict__ d1,
    const float* __restrict__ H2, const float* __restrict__ d2,
    float* __restrict__ xout, float* __restrict__ pout,
    float* __restrict__ finalout, int N)
{
    __shared__ float sV1[160], sc1[16], sV2[128], sc2[8];
    __shared__ float sW1[288], sb1[32], sW2[1024], sb2[32], sW3[32], sbx[1];
    __shared__ float sH1[128], sd1[16], sH2[16], sdx[1];
    int tid = threadIdx.x;
    load_smem(sV1, V1, 160, tid, 512);
    load_smem(sc1, c1, 16, tid, 512);
    load_smem(sV2, V2, 128, tid, 512);
    load_smem(sc2, c2, 8, tid, 512);
    if (!LAST) {
        load_smem(sW1, W1, 288, tid, 512);
        load_smem(sb1, b1, 32, tid, 512);
        load_smem(sW2, W2, 1024, tid, 512);
        load_smem(sb2, b2, 32, tid, 512);
        load_smem(sW3, W3, 32, tid, 512);
        if (tid == 0) sbx[0] = b3[0];
    } else {
        load_smem(sH1, H1, 128, tid, 512);
        load_smem(sd1, d1, 16, tid, 512);
        load_smem(sH2, H2, 16, tid, 512);
        if (tid == 0) sdx[0] = d2[0];
    }
    __syncthreads();

    int bkt = blockIdx.x;
    int n = bkt * NPB + tid;
    if (n >= N) return;

    float aggv = 0.0f;
#pragma unroll
    for (int s = 0; s < S_SPLIT; ++s)
        aggv += aggpart[(size_t)(bkt * S_SPLIT + s) * NPB + tid];

    float t[10];
#pragma unroll
    for (int i = 0; i < 9; ++i) t[i] = xin[(size_t)n*9 + i];
    t[9] = aggv;

    float u[16];
#pragma unroll
    for (int j = 0; j < 16; ++j) u[j] = sc1[j];
#pragma unroll
    for (int i = 0; i < 10; ++i) {
        float v = t[i];
#pragma unroll
        for (int j = 0; j < 16; ++j) u[j] = fmaf(v, sV1[i*16+j], u[j]);
    }
#pragma unroll
    for (int j = 0; j < 16; ++j) u[j] = fmaxf(u[j], 0.0f);

    float comb[8];
#pragma unroll
    for (int j = 0; j < 8; ++j) comb[j] = sc2[j];
#pragma unroll
    for (int i = 0; i < 16; ++i) {
        float v = u[i];
#pragma unroll
        for (int j = 0; j < 8; ++j) comb[j] = fmaf(v, sV2[i*8+j], comb[j]);
    }
#pragma unroll
    for (int j = 0; j < 8; ++j) comb[j] = fmaxf(comb[j], 0.0f);

    if (!LAST) {
        float xnew[9];
        xnew[0] = t[0];
#pragma unroll
        for (int j = 0; j < 8; ++j) xnew[1+j] = comb[j];
#pragma unroll
        for (int i = 0; i < 9; ++i) xout[(size_t)n*9 + i] = xnew[i];
        pout[n] = mlp1_eval(xnew, sW1, sb1, sW2, sb2, sW3, sbx[0]);
    } else {
        float hh[16];
#pragma unroll
        for (int j = 0; j < 16; ++j) hh[j] = sd1[j];
#pragma unroll
        for (int i = 0; i < 8; ++i) {
            float v = comb[i];
#pragma unroll
            for (int j = 0; j < 16; ++j) hh[j] = fmaf(v, sH1[i*16+j], hh[j]);
        }
        float o = sdx[0];
#pragma unroll
        for (int j = 0; j < 16; ++j) o = fmaf(fmaxf(hh[j], 0.0f), sH2[j], o);
        finalout[n] = 1.0f / (1.0f + __expf(-o));
    }
}

// ---- fallback (atomic path) kernels ----

__global__ __launch_bounds__(256) void scatter_kernel4(
    const float* __restrict__ p, const int* __restrict__ src, const int* __restrict__ dst,
    const float* __restrict__ eattr, float* __restrict__ agg, int E)
{
    int i = (blockIdx.x * 256 + threadIdx.x) * 4;
    if (i + 3 < E) {
        int4   s = *(const int4*)(src + i);
        int4   d = *(const int4*)(dst + i);
        float4 a = *(const float4*)(eattr + i);
        atomicAdd(&agg[d.x], p[s.x] * a.x);
        atomicAdd(&agg[d.y], p[s.y] * a.y);
        atomicAdd(&agg[d.z], p[s.z] * a.z);
        atomicAdd(&agg[d.w], p[s.w] * a.w);
    } else {
        for (; i < E; ++i) atomicAdd(&agg[dst[i]], p[src[i]] * eattr[i]);
    }
}

template<bool LAST>
__global__ __launch_bounds__(256) void node_kernel(
    const float* __restrict__ xin, const float* __restrict__ agg,
    const float* __restrict__ V1, const float* __restrict__ c1,
    const float* __restrict__ V2, const float* __restrict__ c2,
    const float* __restrict__ W1, const float* __restrict__ b1,
    const float* __restrict__ W2, const float* __restrict__ b2,
    const float* __restrict__ W3, const float* __restrict__ b3,
    const float* __restrict__ H1, const float* __restrict__ d1,
    const float* __restrict__ H2, const float* __restrict__ d2,
    float* __restrict__ xout, float* __restrict__ pout,
    float* __restrict__ finalout, int N)
{
    __shared__ float sV1[160], sc1[16], sV2[128], sc2[8];
    __shared__ float sW1[288], sb1[32], sW2[1024], sb2[32], sW3[32], sbx[1];
    __shared__ float sH1[128], sd1[16], sH2[16], sdx[1];
    int tid = threadIdx.x;
    load_smem(sV1, V1, 160, tid, 256);
    load_smem(sc1, c1, 16, tid, 256);
    load_smem(sV2, V2, 128, tid, 256);
    load_smem(sc2, c2, 8, tid, 256);
    if (!LAST) {
        load_smem(sW1, W1, 288, tid, 256);
        load_smem(sb1, b1, 32, tid, 256);
        load_smem(sW2, W2, 1024, tid, 256);
        load_smem(sb2, b2, 32, tid, 256);
        load_smem(sW3, W3, 32, tid, 256);
        if (tid == 0) sbx[0] = b3[0];
    } else {
        load_smem(sH1, H1, 128, tid, 256);
        load_smem(sd1, d1, 16, tid, 256);
        load_smem(sH2, H2, 16, tid, 256);
        if (tid == 0) sdx[0] = d2[0];
    }
    __syncthreads();
    int n = blockIdx.x * 256 + tid;
    if (n >= N) return;

    float t[10];
#pragma unroll
    for (int i = 0; i < 9; ++i) t[i] = xin[(size_t)n*9 + i];
    t[9] = agg[n];

    float u[16];
#pragma unroll
    for (int j = 0; j < 16; ++j) u[j] = sc1[j];
#pragma unroll
    for (int i = 0; i < 10; ++i) {
        float v = t[i];
#pragma unroll
        for (int j = 0; j < 16; ++j) u[j] = fmaf(v, sV1[i*16+j], u[j]);
    }
#pragma unroll
    for (int j = 0; j < 16; ++j) u[j] = fmaxf(u[j], 0.0f);

    float comb[8];
#pragma unroll
    for (int j = 0; j < 8; ++j) comb[j] = sc2[j];
#pragma unroll
    for (int i = 0; i < 16; ++i) {
        float v = u[i];
#pragma unroll
        for (int j = 0; j < 8; ++j) comb[j] = fmaf(v, sV2[i*8+j], comb[j]);
    }
#pragma unroll
    for (int j = 0; j < 8; ++j) comb[j] = fmaxf(comb[j], 0.0f);

    if (!LAST) {
        float xnew[9];
        xnew[0] = t[0];
#pragma unroll
        for (int j = 0; j < 8; ++j) xnew[1+j] = comb[j];
#pragma unroll
        for (int i = 0; i < 9; ++i) xout[(size_t)n*9 + i] = xnew[i];
        pout[n] = mlp1_eval(xnew, sW1, sb1, sW2, sb2, sW3, sbx[0]);
    } else {
        float hh[16];
#pragma unroll
        for (int j = 0; j < 16; ++j) hh[j] = sd1[j];
#pragma unroll
        for (int i = 0; i < 8; ++i) {
            float v = comb[i];
#pragma unroll
            for (int j = 0; j < 16; ++j) hh[j] = fmaf(v, sH1[i*16+j], hh[j]);
        }
        float o = sdx[0];
#pragma unroll
        for (int j = 0; j < 16; ++j) o = fmaf(fmaxf(hh[j], 0.0f), sH2[j], o);
        finalout[n] = 1.0f / (1.0f + __expf(-o));
    }
}

extern "C" void kernel_launch(void* const* d_in, const int* in_sizes, int n_in,
                              void* d_out, int out_size, void* d_ws, size_t ws_size,
                              hipStream_t stream)
{
    const float* x     = (const float*)d_in[0];
    const float* eattr = (const float*)d_in[1];
    const int*   eidx  = (const int*)d_in[2];
    const float *W1=(const float*)d_in[3],  *b1=(const float*)d_in[4];
    const float *W2=(const float*)d_in[5],  *b2=(const float*)d_in[6];
    const float *W3=(const float*)d_in[7],  *b3=(const float*)d_in[8];
    const float *V1=(const float*)d_in[9],  *c1=(const float*)d_in[10];
    const float *V2=(const float*)d_in[11], *c2=(const float*)d_in[12];
    const float *H1=(const float*)d_in[13], *d1=(const float*)d_in[14];
    const float *H2=(const float*)d_in[15], *d2=(const float*)d_in[16];
    int N = in_sizes[0] / 9;
    int E = in_sizes[1];
    const int* src = eidx;
    const int* dst = eidx + E;
    float* out = (float*)d_out;
    int B = (N + NPB - 1) / NPB;

    size_t need = (size_t)E * 8                      // ia
                + (size_t)N * 9 * 4                  // xc (in-place after round 1)
                + (size_t)N * 4 * 2                  // pA, pB
                + (size_t)B * S_SPLIT * NPB * 4      // aggpart
                + (size_t)MAXB * 4 * 3 + 64;         // count, cursor, base(+1)

    dim3 thr256(256), thr512(512);
    dim3 blkN((N + 255) / 256);
    bool packable = ((long long)N << NPB_SHIFT) < (1LL << 32);

    if (B <= MAXB && packable && ws_size >= need) {
        char* w = (char*)d_ws;
        int2*  ia      = (int2*)w;   w += (size_t)E * 8;
        float* xc      = (float*)w;  w += (size_t)N * 9 * 4;
        float* pA      = (float*)w;  w += (size_t)N * 4;
        float* pB      = (float*)w;  w += (size_t)N * 4;
        float* aggpart = (float*)w;  w += (size_t)B * S_SPLIT * NPB * 4;
        uint*  count   = (uint*)w;   w += (size_t)MAXB * 4;
        uint*  cursor  = (uint*)w;   w += (size_t)MAXB * 4;
        uint*  base    = (uint*)w;

        dim3 blkP((E + CHUNK - 1) / CHUNK);
        dim3 blkA(B * S_SPLIT);
        dim3 blkB(B);

        p0_kernel<<<blkN, thr256, 0, stream>>>(x, W1,b1,W2,b2,W3,b3, pA, count, nullptr, N);
        hist_kernel2<<<dim3(NBLK_H), thr256, 0, stream>>>(dst, count, E, B);
        scan_kernel<<<dim3(1), thr256, 0, stream>>>(count, base, cursor, B);
        partition_kernel<<<blkP, thr256, 0, stream>>>(dst, src, eattr, cursor, ia, E, B);

        // round 1: x -> xc
        agg_kernel<<<blkA, thr512, 0, stream>>>(ia, base, pA, aggpart);
        node_kernel2<false><<<blkB, thr512, 0, stream>>>(x, aggpart,
            V1,c1,V2,c2, W1,b1,W2,b2,W3,b3, H1,d1,H2,d2, xc, pB, nullptr, N);
        // round 2: xc -> xc (in place)
        agg_kernel<<<blkA, thr512, 0, stream>>>(ia, base, pB, aggpart);
        node_kernel2<false><<<blkB, thr512, 0, stream>>>(xc, aggpart,
            V1,c1,V2,c2, W1,b1,W2,b2,W3,b3, H1,d1,H2,d2, xc, pA, nullptr, N);
        // round 3: xc -> out
        agg_kernel<<<blkA, thr512, 0, stream>>>(ia, base, pA, aggpart);
        node_kernel2<true><<<blkB, thr512, 0, stream>>>(xc, aggpart,
            V1,c1,V2,c2, W1,b1,W2,b2,W3,b3, H1,d1,H2,d2, nullptr, nullptr, out, N);
    } else {
        // fallback: atomic path (ws ~8.8 MB)
        float* ws   = (float*)d_ws;
        float* xcA  = ws;
        float* xcB  = xcA + (size_t)N * 9;
        float* p    = xcB + (size_t)N * 9;
        float* agg3 = p + N;
        dim3 blkE4(((E + 3) / 4 + 255) / 256);

        p0_kernel<<<blkN, thr256, 0, stream>>>(x, W1,b1,W2,b2,W3,b3, p, nullptr, agg3, N);
        scatter_kernel4<<<blkE4, thr256, 0, stream>>>(p, src, dst, eattr, agg3, E);
        node_kernel<false><<<blkN, thr256, 0, stream>>>(x, agg3, V1,c1,V2,c2, W1,b1,W2,b2,W3,b3,
                                                        H1,d1,H2,d2, xcA, p, nullptr, N);
        scatter_kernel4<<<blkE4, thr256, 0, stream>>>(p, src, dst, eattr, agg3 + N, E);
        node_kernel<false><<<blkN, thr256, 0, stream>>>(xcA, agg3 + N, V1,c1,V2,c2, W1,b1,W2,b2,W3,b3,
                                                        H1,d1,H2,d2, xcB, p, nullptr, N);
        scatter_kernel4<<<blkE4, thr256, 0, stream>>>(p, src, dst, eattr, agg3 + 2*(size_t)N, E);
        node_kernel<true><<<blkN, thr256, 0, stream>>>(xcB, agg3 + 2*(size_t)N, V1,c1,V2,c2,
                                                       W1,b1,W2,b2,W3,b3, H1,d1,H2,d2,
                                                       nullptr, nullptr, out, N);
    }
}

// Round 6
// 171.873 us; speedup vs baseline: 1.1296x; 1.1296x over previous
//
#include <hip/hip_runtime.h>

typedef unsigned int uint;
typedef unsigned char uchar;

// AirMPNN R6.
// p[n] = sigmoid(mlp1(xc[n])) per NODE (mlp1 depends only on source node).
// Edge phase: one per-call partition into B=ceil(N/2048) dst-buckets via
// direct-write counting sort (no LDS staging, tiny LDS, high occupancy),
// then 3 rounds of {split-16 ILP-8 LDS aggregation -> aggpart, node MLP}.

#define NPB 2048       // nodes per bucket
#define NPB_SHIFT 11
#define MAXB 256       // max buckets (N <= 524288)
#define PCHUNK 4096    // edges per partition block
#define S_SPLIT 16     // sub-blocks per bucket in aggregation
#define NBLK_H 1024

__device__ __forceinline__ void load_smem(float* dstp, const float* __restrict__ srcp,
                                          int n, int tid, int nthreads) {
    for (int i = tid; i < n; i += nthreads) dstp[i] = srcp[i];
}

// sigmoid(mlp1(xj)): 9 -> 32 relu -> 32 relu -> 1 sigmoid
__device__ __forceinline__ float mlp1_eval(const float* xj,
    const float* sW1, const float* sb1, const float* sW2, const float* sb2,
    const float* sW3, float sb3)
{
    float h1[32];
#pragma unroll
    for (int j = 0; j < 32; ++j) h1[j] = sb1[j];
#pragma unroll
    for (int i = 0; i < 9; ++i) {
        float v = xj[i];
#pragma unroll
        for (int j = 0; j < 32; ++j) h1[j] = fmaf(v, sW1[i*32+j], h1[j]);
    }
#pragma unroll
    for (int j = 0; j < 32; ++j) h1[j] = fmaxf(h1[j], 0.0f);
    float h2[32];
#pragma unroll
    for (int j = 0; j < 32; ++j) h2[j] = sb2[j];
#pragma unroll
    for (int i = 0; i < 32; ++i) {
        float v = h1[i];
#pragma unroll
        for (int j = 0; j < 32; ++j) h2[j] = fmaf(v, sW2[i*32+j], h2[j]);
    }
    float m = sb3;
#pragma unroll
    for (int i = 0; i < 32; ++i) m = fmaf(fmaxf(h2[i], 0.0f), sW3[i], m);
    return 1.0f / (1.0f + __expf(-m));
}

// p0: p[n] = sigmoid(mlp1(x[n])); block 0 zeroes count[]; fallback zeroes agg3
__global__ __launch_bounds__(256) void p0_kernel(
    const float* __restrict__ x,
    const float* __restrict__ W1, const float* __restrict__ b1,
    const float* __restrict__ W2, const float* __restrict__ b2,
    const float* __restrict__ W3, const float* __restrict__ b3,
    float* __restrict__ p, uint* __restrict__ count, float* __restrict__ agg3, int N)
{
    __shared__ float sW1[288], sb1[32], sW2[1024], sb2[32], sW3[32], sb3s[1];
    int tid = threadIdx.x;
    load_smem(sW1, W1, 288, tid, 256);
    load_smem(sb1, b1, 32, tid, 256);
    load_smem(sW2, W2, 1024, tid, 256);
    load_smem(sb2, b2, 32, tid, 256);
    load_smem(sW3, W3, 32, tid, 256);
    if (tid == 0) sb3s[0] = b3[0];
    __syncthreads();
    if (count && blockIdx.x == 0) count[tid] = 0u;   // MAXB == 256
    int n = blockIdx.x * 256 + tid;
    if (n >= N) return;
    if (agg3) { agg3[n] = 0.0f; agg3[N + n] = 0.0f; agg3[2*(size_t)N + n] = 0.0f; }
    float xj[9];
#pragma unroll
    for (int i = 0; i < 9; ++i) xj[i] = x[(size_t)n*9 + i];
    p[n] = mlp1_eval(xj, sW1, sb1, sW2, sb2, sW3, sb3s[0]);
}

// bin totals: LDS hist + one global atomic per (block,bin)
__global__ __launch_bounds__(256) void hist_kernel2(
    const int* __restrict__ dst, uint* __restrict__ count, int E, int B)
{
    __shared__ uint hist[MAXB];
    int tid = threadIdx.x;
    for (int i = tid; i < MAXB; i += 256) hist[i] = 0u;
    __syncthreads();
    int total = gridDim.x * 256;
    int gid = blockIdx.x * 256 + tid;
    int E4 = E >> 2;
    const int4* dst4 = (const int4*)dst;
    for (int i = gid; i < E4; i += total) {
        int4 d = dst4[i];
        atomicAdd(&hist[((uint)d.x) >> NPB_SHIFT], 1u);
        atomicAdd(&hist[((uint)d.y) >> NPB_SHIFT], 1u);
        atomicAdd(&hist[((uint)d.z) >> NPB_SHIFT], 1u);
        atomicAdd(&hist[((uint)d.w) >> NPB_SHIFT], 1u);
    }
    for (int e = 4*E4 + gid; e < E; e += total)
        atomicAdd(&hist[((uint)dst[e]) >> NPB_SHIFT], 1u);
    __syncthreads();
    for (int b = tid; b < B; b += 256)
        if (hist[b]) atomicAdd(&count[b], hist[b]);
}

// exclusive scan of EVEN-PADDED counts -> base[], cursor[]  (even bases keep
// int4 loads in agg aligned; agg uses true count[] for the end bound)
__global__ __launch_bounds__(256) void scan_kernel(
    const uint* __restrict__ count, uint* __restrict__ base,
    uint* __restrict__ cursor, int B)
{
    __shared__ uint s[MAXB];
    int t = threadIdx.x;
    uint v = (t < B) ? ((count[t] + 1u) & ~1u) : 0u;
    s[t] = v;
    __syncthreads();
    for (int off = 1; off < MAXB; off <<= 1) {
        uint xv = (t >= off) ? s[t - off] : 0u;
        __syncthreads();
        s[t] += xv;
        __syncthreads();
    }
    uint excl = s[t] - v;
    if (t < B) { base[t] = excl; cursor[t] = excl; }
    else       { cursor[t] = 0u; }
    if (t == B - 1) base[B] = s[t];
}

// Direct-write counting-sort partition: tiny LDS (512B), keys cached in regs,
// one global cursor atomic per (block,bin), scattered-but-clustered writes
// (runs of ~PCHUNK/B ~ 84 edges per (block,bin) merge in L2).
__global__ __launch_bounds__(512) void partition_kernel(
    const int* __restrict__ dst, const int* __restrict__ src,
    const float* __restrict__ ea, uint* __restrict__ cursor,
    int2* __restrict__ ia, int E, int B)
{
    __shared__ uint hist[64];
    __shared__ uint gbase[64];
    int tid = threadIdx.x;
    int start = blockIdx.x * PCHUNK;
    int n = min(E - start, PCHUNK);
    if (tid < 64) hist[tid] = 0u;
    __syncthreads();
    uint dc[8];
    // pass 1: coalesced key reads (cache in regs), LDS count
#pragma unroll
    for (int j = 0; j < 2; ++j) {
        int p4 = tid + j*512;
        int e  = p4 << 2;
        if (e + 3 < n) {
            int4 d = ((const int4*)(dst + start))[p4];
            dc[j*4+0] = (uint)d.x; dc[j*4+1] = (uint)d.y;
            dc[j*4+2] = (uint)d.z; dc[j*4+3] = (uint)d.w;
            atomicAdd(&hist[((uint)d.x) >> NPB_SHIFT], 1u);
            atomicAdd(&hist[((uint)d.y) >> NPB_SHIFT], 1u);
            atomicAdd(&hist[((uint)d.z) >> NPB_SHIFT], 1u);
            atomicAdd(&hist[((uint)d.w) >> NPB_SHIFT], 1u);
        } else {
#pragma unroll
            for (int k = 0; k < 4; ++k) {
                if (e + k < n) {
                    uint d = (uint)dst[start + e + k];
                    dc[j*4+k] = d;
                    atomicAdd(&hist[d >> NPB_SHIFT], 1u);
                } else dc[j*4+k] = 0xFFFFFFFFu;
            }
        }
    }
    __syncthreads();
    if (tid < 64) {
        uint c = (tid < B) ? hist[tid] : 0u;
        gbase[tid] = c ? atomicAdd(&cursor[tid], c) : 0u;
        hist[tid] = 0u;            // reuse as local bump cursor
    }
    __syncthreads();
    // pass 2: read payload coalesced, write direct at reserved positions
#pragma unroll
    for (int j = 0; j < 2; ++j) {
        int p4 = tid + j*512;
        int e  = p4 << 2;
        if (e + 3 < n) {
            int4   s4 = ((const int4*)(src + start))[p4];
            float4 a4 = ((const float4*)(ea + start))[p4];
            int sv[4] = {s4.x, s4.y, s4.z, s4.w};
            float av[4] = {a4.x, a4.y, a4.z, a4.w};
#pragma unroll
            for (int k = 0; k < 4; ++k) {
                uint d = dc[j*4+k];
                uint b = d >> NPB_SHIFT;
                uint pos = gbase[b] + atomicAdd(&hist[b], 1u);
                int2 v;
                v.x = (int)(((uint)sv[k] << NPB_SHIFT) | (d & (NPB - 1)));
                v.y = __float_as_int(av[k]);
                ia[pos] = v;
            }
        } else {
#pragma unroll
            for (int k = 0; k < 4; ++k) {
                if (e + k < n) {
                    uint d = dc[j*4+k];
                    uint b = d >> NPB_SHIFT;
                    uint pos = gbase[b] + atomicAdd(&hist[b], 1u);
                    int2 v;
                    v.x = (int)(((uint)src[start + e + k] << NPB_SHIFT) | (d & (NPB - 1)));
                    v.y = __float_as_int(ea[start + e + k]);
                    ia[pos] = v;
                }
            }
        }
    }
}

// split-16 aggregation, 8 edges/thread as 4 independent int4 loads:
// high ILP on the p-gather latency chain; LDS atomics into aggl[2048].
__global__ __launch_bounds__(512) void agg_kernel(
    const int2* __restrict__ ia, const uint* __restrict__ base,
    const uint* __restrict__ count, const float* __restrict__ p_in,
    float* __restrict__ aggpart)
{
    __shared__ float aggl[NPB];
    int tid = threadIdx.x;
    int bkt = blockIdx.x / S_SPLIT;
    int sub = blockIdx.x % S_SPLIT;
#pragma unroll
    for (int k = 0; k < NPB/512; ++k) aggl[tid + k*512] = 0.0f;
    __syncthreads();
    uint e0 = base[bkt];
    uint e1 = e0 + count[bkt];
    for (uint estart = e0 + (uint)sub * 4096u; estart < e1;
         estart += (uint)S_SPLIT * 4096u) {
#pragma unroll
        for (int j = 0; j < 4; ++j) {
            uint e = estart + 2u * ((uint)tid + (uint)j * 512u);
            if (e + 1u < e1) {
                int4 w = *(const int4*)(ia + e);          // two edges, aligned
                float m0 = p_in[(uint)w.x >> NPB_SHIFT] * __int_as_float(w.y);
                float m1 = p_in[(uint)w.z >> NPB_SHIFT] * __int_as_float(w.w);
                atomicAdd(&aggl[(uint)w.x & (NPB - 1)], m0);
                atomicAdd(&aggl[(uint)w.z & (NPB - 1)], m1);
            } else if (e < e1) {
                int2 w = ia[e];
                atomicAdd(&aggl[(uint)w.x & (NPB - 1)],
                          p_in[(uint)w.x >> NPB_SHIFT] * __int_as_float(w.y));
            }
        }
    }
    __syncthreads();
#pragma unroll
    for (int k = 0; k < NPB/512; ++k)
        aggpart[(size_t)blockIdx.x * NPB + tid + k*512] = aggl[tid + k*512];
}

// node MLP, 256-thr blocks (grid = ceil(N/256)); sums S_SPLIT partials.
// xin==xout in-place is safe: each thread touches only its own row.
template<bool LAST>
__global__ __launch_bounds__(256) void node_kernel3(
    const float* __restrict__ xin, const float* __restrict__ aggpart,
    const float* __restrict__ V1, const float* __restrict__ c1,
    const float* __restrict__ V2, const float* __restrict__ c2,
    const float* __restrict__ W1, const float* __restrict__ b1,
    const float* __restrict__ W2, const float* __restrict__ b2,
    const float* __restrict__ W3, const float* __restrict__ b3,
    const float* __restrict__ H1, const float* __restrict__ d1,
    const float* __restrict__ H2, const float* __restrict__ d2,
    float* __restrict__ xout, float* __restrict__ pout,
    float* __restrict__ finalout, int N)
{
    __shared__ float sV1[160], sc1[16], sV2[128], sc2[8];
    __shared__ float sW1[288], sb1[32], sW2[1024], sb2[32], sW3[32], sbx[1];
    __shared__ float sH1[128], sd1[16], sH2[16], sdx[1];
    int tid = threadIdx.x;
    load_smem(sV1, V1, 160, tid, 256);
    load_smem(sc1, c1, 16, tid, 256);
    load_smem(sV2, V2, 128, tid, 256);
    load_smem(sc2, c2, 8, tid, 256);
    if (!LAST) {
        load_smem(sW1, W1, 288, tid, 256);
        load_smem(sb1, b1, 32, tid, 256);
        load_smem(sW2, W2, 1024, tid, 256);
        load_smem(sb2, b2, 32, tid, 256);
        load_smem(sW3, W3, 32, tid, 256);
        if (tid == 0) sbx[0] = b3[0];
    } else {
        load_smem(sH1, H1, 128, tid, 256);
        load_smem(sd1, d1, 16, tid, 256);
        load_smem(sH2, H2, 16, tid, 256);
        if (tid == 0) sdx[0] = d2[0];
    }
    __syncthreads();

    int n = blockIdx.x * 256 + tid;
    if (n >= N) return;

    int bkt = n >> NPB_SHIFT, slot = n & (NPB - 1);
    const float* ap = aggpart + (size_t)bkt * S_SPLIT * NPB + slot;
    float aggv = 0.0f;
#pragma unroll
    for (int s = 0; s < S_SPLIT; ++s) aggv += ap[(size_t)s * NPB];

    float t[10];
#pragma unroll
    for (int i = 0; i < 9; ++i) t[i] = xin[(size_t)n*9 + i];
    t[9] = aggv;

    float u[16];
#pragma unroll
    for (int j = 0; j < 16; ++j) u[j] = sc1[j];
#pragma unroll
    for (int i = 0; i < 10; ++i) {
        float v = t[i];
#pragma unroll
        for (int j = 0; j < 16; ++j) u[j] = fmaf(v, sV1[i*16+j], u[j]);
    }
#pragma unroll
    for (int j = 0; j < 16; ++j) u[j] = fmaxf(u[j], 0.0f);

    float comb[8];
#pragma unroll
    for (int j = 0; j < 8; ++j) comb[j] = sc2[j];
#pragma unroll
    for (int i = 0; i < 16; ++i) {
        float v = u[i];
#pragma unroll
        for (int j = 0; j < 8; ++j) comb[j] = fmaf(v, sV2[i*8+j], comb[j]);
    }
#pragma unroll
    for (int j = 0; j < 8; ++j) comb[j] = fmaxf(comb[j], 0.0f);

    if (!LAST) {
        float xnew[9];
        xnew[0] = t[0];
#pragma unroll
        for (int j = 0; j < 8; ++j) xnew[1+j] = comb[j];
#pragma unroll
        for (int i = 0; i < 9; ++i) xout[(size_t)n*9 + i] = xnew[i];
        pout[n] = mlp1_eval(xnew, sW1, sb1, sW2, sb2, sW3, sbx[0]);
    } else {
        float hh[16];
#pragma unroll
        for (int j = 0; j < 16; ++j) hh[j] = sd1[j];
#pragma unroll
        for (int i = 0; i < 8; ++i) {
            float v = comb[i];
#pragma unroll
            for (int j = 0; j < 16; ++j) hh[j] = fmaf(v, sH1[i*16+j], hh[j]);
        }
        float o = sdx[0];
#pragma unroll
        for (int j = 0; j < 16; ++j) o = fmaf(fmaxf(hh[j], 0.0f), sH2[j], o);
        finalout[n] = 1.0f / (1.0f + __expf(-o));
    }
}

// ---- fallback (atomic path) kernels ----

__global__ __launch_bounds__(256) void scatter_kernel4(
    const float* __restrict__ p, const int* __restrict__ src, const int* __restrict__ dst,
    const float* __restrict__ eattr, float* __restrict__ agg, int E)
{
    int i = (blockIdx.x * 256 + threadIdx.x) * 4;
    if (i + 3 < E) {
        int4   s = *(const int4*)(src + i);
        int4   d = *(const int4*)(dst + i);
        float4 a = *(const float4*)(eattr + i);
        atomicAdd(&agg[d.x], p[s.x] * a.x);
        atomicAdd(&agg[d.y], p[s.y] * a.y);
        atomicAdd(&agg[d.z], p[s.z] * a.z);
        atomicAdd(&agg[d.w], p[s.w] * a.w);
    } else {
        for (; i < E; ++i) atomicAdd(&agg[dst[i]], p[src[i]] * eattr[i]);
    }
}

template<bool LAST>
__global__ __launch_bounds__(256) void node_kernel(
    const float* __restrict__ xin, const float* __restrict__ agg,
    const float* __restrict__ V1, const float* __restrict__ c1,
    const float* __restrict__ V2, const float* __restrict__ c2,
    const float* __restrict__ W1, const float* __restrict__ b1,
    const float* __restrict__ W2, const float* __restrict__ b2,
    const float* __restrict__ W3, const float* __restrict__ b3,
    const float* __restrict__ H1, const float* __restrict__ d1,
    const float* __restrict__ H2, const float* __restrict__ d2,
    float* __restrict__ xout, float* __restrict__ pout,
    float* __restrict__ finalout, int N)
{
    __shared__ float sV1[160], sc1[16], sV2[128], sc2[8];
    __shared__ float sW1[288], sb1[32], sW2[1024], sb2[32], sW3[32], sbx[1];
    __shared__ float sH1[128], sd1[16], sH2[16], sdx[1];
    int tid = threadIdx.x;
    load_smem(sV1, V1, 160, tid, 256);
    load_smem(sc1, c1, 16, tid, 256);
    load_smem(sV2, V2, 128, tid, 256);
    load_smem(sc2, c2, 8, tid, 256);
    if (!LAST) {
        load_smem(sW1, W1, 288, tid, 256);
        load_smem(sb1, b1, 32, tid, 256);
        load_smem(sW2, W2, 1024, tid, 256);
        load_smem(sb2, b2, 32, tid, 256);
        load_smem(sW3, W3, 32, tid, 256);
        if (tid == 0) sbx[0] = b3[0];
    } else {
        load_smem(sH1, H1, 128, tid, 256);
        load_smem(sd1, d1, 16, tid, 256);
        load_smem(sH2, H2, 16, tid, 256);
        if (tid == 0) sdx[0] = d2[0];
    }
    __syncthreads();
    int n = blockIdx.x * 256 + tid;
    if (n >= N) return;

    float t[10];
#pragma unroll
    for (int i = 0; i < 9; ++i) t[i] = xin[(size_t)n*9 + i];
    t[9] = agg[n];

    float u[16];
#pragma unroll
    for (int j = 0; j < 16; ++j) u[j] = sc1[j];
#pragma unroll
    for (int i = 0; i < 10; ++i) {
        float v = t[i];
#pragma unroll
        for (int j = 0; j < 16; ++j) u[j] = fmaf(v, sV1[i*16+j], u[j]);
    }
#pragma unroll
    for (int j = 0; j < 16; ++j) u[j] = fmaxf(u[j], 0.0f);

    float comb[8];
#pragma unroll
    for (int j = 0; j < 8; ++j) comb[j] = sc2[j];
#pragma unroll
    for (int i = 0; i < 16; ++i) {
        float v = u[i];
#pragma unroll
        for (int j = 0; j < 8; ++j) comb[j] = fmaf(v, sV2[i*8+j], comb[j]);
    }
#pragma unroll
    for (int j = 0; j < 8; ++j) comb[j] = fmaxf(comb[j], 0.0f);

    if (!LAST) {
        float xnew[9];
        xnew[0] = t[0];
#pragma unroll
        for (int j = 0; j < 8; ++j) xnew[1+j] = comb[j];
#pragma unroll
        for (int i = 0; i < 9; ++i) xout[(size_t)n*9 + i] = xnew[i];
        pout[n] = mlp1_eval(xnew, sW1, sb1, sW2, sb2, sW3, sbx[0]);
    } else {
        float hh[16];
#pragma unroll
        for (int j = 0; j < 16; ++j) hh[j] = sd1[j];
#pragma unroll
        for (int i = 0; i < 8; ++i) {
            float v = comb[i];
#pragma unroll
            for (int j = 0; j < 16; ++j) hh[j] = fmaf(v, sH1[i*16+j], hh[j]);
        }
        float o = sdx[0];
#pragma unroll
        for (int j = 0; j < 16; ++j) o = fmaf(fmaxf(hh[j], 0.0f), sH2[j], o);
        finalout[n] = 1.0f / (1.0f + __expf(-o));
    }
}

extern "C" void kernel_launch(void* const* d_in, const int* in_sizes, int n_in,
                              void* d_out, int out_size, void* d_ws, size_t ws_size,
                              hipStream_t stream)
{
    const float* x     = (const float*)d_in[0];
    const float* eattr = (const float*)d_in[1];
    const int*   eidx  = (const int*)d_in[2];
    const float *W1=(const float*)d_in[3],  *b1=(const float*)d_in[4];
    const float *W2=(const float*)d_in[5],  *b2=(const float*)d_in[6];
    const float *W3=(const float*)d_in[7],  *b3=(const float*)d_in[8];
    const float *V1=(const float*)d_in[9],  *c1=(const float*)d_in[10];
    const float *V2=(const float*)d_in[11], *c2=(const float*)d_in[12];
    const float *H1=(const float*)d_in[13], *d1=(const float*)d_in[14];
    const float *H2=(const float*)d_in[15], *d2=(const float*)d_in[16];
    int N = in_sizes[0] / 9;
    int E = in_sizes[1];
    const int* src = eidx;
    const int* dst = eidx + E;
    float* out = (float*)d_out;
    int B = (N + NPB - 1) / NPB;

    size_t need = (size_t)(E + MAXB) * 8             // ia (+ even padding slack)
                + (size_t)N * 9 * 4                  // xc
                + (size_t)N * 4 * 2                  // pA, pB
                + (size_t)B * S_SPLIT * NPB * 4      // aggpart
                + (size_t)MAXB * 4 * 3 + 64;         // count, cursor, base(+1)

    dim3 thr256(256), thr512(512);
    dim3 blkN((N + 255) / 256);
    bool packable = ((long long)N << NPB_SHIFT) < (1LL << 32);

    if (B <= MAXB && packable && ws_size >= need) {
        char* w = (char*)d_ws;
        int2*  ia      = (int2*)w;   w += (size_t)(E + MAXB) * 8;
        float* xc      = (float*)w;  w += (size_t)N * 9 * 4;
        float* pA      = (float*)w;  w += (size_t)N * 4;
        float* pB      = (float*)w;  w += (size_t)N * 4;
        float* aggpart = (float*)w;  w += (size_t)B * S_SPLIT * NPB * 4;
        uint*  count   = (uint*)w;   w += (size_t)MAXB * 4;
        uint*  cursor  = (uint*)w;   w += (size_t)MAXB * 4;
        uint*  base    = (uint*)w;

        dim3 blkP((E + PCHUNK - 1) / PCHUNK);
        dim3 blkA(B * S_SPLIT);

        p0_kernel<<<blkN, thr256, 0, stream>>>(x, W1,b1,W2,b2,W3,b3, pA, count, nullptr, N);
        hist_kernel2<<<dim3(NBLK_H), thr256, 0, stream>>>(dst, count, E, B);
        scan_kernel<<<dim3(1), thr256, 0, stream>>>(count, base, cursor, B);
        partition_kernel<<<blkP, thr512, 0, stream>>>(dst, src, eattr, cursor, ia, E, B);

        // round 1: x -> xc
        agg_kernel<<<blkA, thr512, 0, stream>>>(ia, base, count, pA, aggpart);
        node_kernel3<false><<<blkN, thr256, 0, stream>>>(x, aggpart,
            V1,c1,V2,c2, W1,b1,W2,b2,W3,b3, H1,d1,H2,d2, xc, pB, nullptr, N);
        // round 2: xc -> xc (in place)
        agg_kernel<<<blkA, thr512, 0, stream>>>(ia, base, count, pB, aggpart);
        node_kernel3<false><<<blkN, thr256, 0, stream>>>(xc, aggpart,
            V1,c1,V2,c2, W1,b1,W2,b2,W3,b3, H1,d1,H2,d2, xc, pA, nullptr, N);
        // round 3: xc -> out
        agg_kernel<<<blkA, thr512, 0, stream>>>(ia, base, count, pA, aggpart);
        node_kernel3<true><<<blkN, thr256, 0, stream>>>(xc, aggpart,
            V1,c1,V2,c2, W1,b1,W2,b2,W3,b3, H1,d1,H2,d2, nullptr, nullptr, out, N);
    } else {
        // fallback: atomic path (ws ~8.8 MB)
        float* ws   = (float*)d_ws;
        float* xcA  = ws;
        float* xcB  = xcA + (size_t)N * 9;
        float* p    = xcB + (size_t)N * 9;
        float* agg3 = p + N;
        dim3 blkE4(((E + 3) / 4 + 255) / 256);

        p0_kernel<<<blkN, thr256, 0, stream>>>(x, W1,b1,W2,b2,W3,b3, p, nullptr, agg3, N);
        scatter_kernel4<<<blkE4, thr256, 0, stream>>>(p, src, dst, eattr, agg3, E);
        node_kernel<false><<<blkN, thr256, 0, stream>>>(x, agg3, V1,c1,V2,c2, W1,b1,W2,b2,W3,b3,
                                                        H1,d1,H2,d2, xcA, p, nullptr, N);
        scatter_kernel4<<<blkE4, thr256, 0, stream>>>(p, src, dst, eattr, agg3 + N, E);
        node_kernel<false><<<blkN, thr256, 0, stream>>>(xcA, agg3 + N, V1,c1,V2,c2, W1,b1,W2,b2,W3,b3,
                                                        H1,d1,H2,d2, xcB, p, nullptr, N);
        scatter_kernel4<<<blkE4, thr256, 0, stream>>>(p, src, dst, eattr, agg3 + 2*(size_t)N, E);
        node_kernel<true><<<blkN, thr256, 0, stream>>>(xcB, agg3 + 2*(size_t)N, V1,c1,V2,c2,
                                                       W1,b1,W2,b2,W3,b3, H1,d1,H2,d2,
                                                       nullptr, nullptr, out, N);
    }
}